// Round 2
// baseline (84.471 us; speedup 1.0000x reference)
//
#include <hip/hip_runtime.h>

#define TW 16
#define TH 16
#define CIN 27
#define HH 64
#define WW 64
#define OC 32

__device__ __forceinline__ float maj3(float a, float b, float c) {
    // Exact closed form of the bipolar 3-input majority-gate simulation (n=3):
    // [ (1+a)(1+b)(1-c) + (1+a)(1-b)(1+c) + (1-a)(1+b)(1+c) + (1+a)(1+b)(1+c) ] / 4 - 1
    //   == (a + b + c - a*b*c) / 2    (all bilinear terms cancel)
    return 0.5f * (a + b + c - a * b * c);
}

__global__ __launch_bounds__(256) void sconv_maj_kernel(
    const float* __restrict__ x,    // [N, CIN, H, W] fp32
    const float* __restrict__ wgt,  // [OC, CIN, 3, 3] fp32
    float* __restrict__ out)        // [N, OC, H, W] fp32
{
    __shared__ float sx[CIN][TH + 2][TW + 2];  // 27*18*18*4 = 34992 B
    __shared__ float sw[CIN * 9];              // 972 B

    const int tx = threadIdx.x;
    const int ty = threadIdx.y;
    const int tid = ty * TW + tx;
    const int tile_w0 = blockIdx.x * TW;
    const int tile_h0 = blockIdx.y * TH;
    const int noc = blockIdx.z;
    const int n  = noc >> 5;   // OC = 32
    const int oc = noc & 31;

    // ---- stage weights for this oc (block-uniform) ----
    if (tid < CIN * 9)
        sw[tid] = wgt[oc * (CIN * 9) + tid];

    // ---- stage x tile with 1-halo, zero padding ----
    const int TOT = CIN * (TH + 2) * (TW + 2);  // 8748
    const float* xn = x + (size_t)n * (CIN * HH * WW);
    for (int idx = tid; idx < TOT; idx += TH * TW) {
        int c   = idx / ((TH + 2) * (TW + 2));
        int rem = idx - c * ((TH + 2) * (TW + 2));
        int r   = rem / (TW + 2);
        int col = rem - r * (TW + 2);
        int gr = tile_h0 + r - 1;
        int gc = tile_w0 + col - 1;
        float v = 0.0f;
        if (gr >= 0 && gr < HH && gc >= 0 && gc < WW)
            v = xn[c * (HH * WW) + gr * WW + gc];
        ((float*)sx)[idx] = v;
    }
    __syncthreads();

    // ---- 5-level majority tree over f = c*9 + ki*3 + kj (243 = 3^5) ----
    float m2[CIN];
    #pragma unroll
    for (int c = 0; c < CIN; ++c) {
        float m1[3];
        #pragma unroll
        for (int ki = 0; ki < 3; ++ki) {
            float p0 = sx[c][ty + ki][tx + 0] * sw[c * 9 + ki * 3 + 0];
            float p1 = sx[c][ty + ki][tx + 1] * sw[c * 9 + ki * 3 + 1];
            float p2 = sx[c][ty + ki][tx + 2] * sw[c * 9 + ki * 3 + 2];
            m1[ki] = maj3(p0, p1, p2);
        }
        m2[c] = maj3(m1[0], m1[1], m1[2]);
    }
    float m3[9];
    #pragma unroll
    for (int g = 0; g < 9; ++g)
        m3[g] = maj3(m2[3 * g], m2[3 * g + 1], m2[3 * g + 2]);
    float m4a = maj3(m3[0], m3[1], m3[2]);
    float m4b = maj3(m3[3], m3[4], m3[5]);
    float m4c = maj3(m3[6], m3[7], m3[8]);
    float res = maj3(m4a, m4b, m4c);

    const int h = tile_h0 + ty;
    const int w = tile_w0 + tx;
    out[(((size_t)n * OC + oc) * HH + h) * WW + w] = res;
}

extern "C" void kernel_launch(void* const* d_in, const int* in_sizes, int n_in,
                              void* d_out, int out_size, void* d_ws, size_t ws_size,
                              hipStream_t stream) {
    const float* x   = (const float*)d_in[0];
    const float* wgt = (const float*)d_in[1];
    float* out = (float*)d_out;

    dim3 block(TW, TH, 1);
    dim3 grid(WW / TW, HH / TH, 2 * OC);  // (4, 4, 64) = 1024 blocks
    sconv_maj_kernel<<<grid, block, 0, stream>>>(x, wgt, out);
}